// Round 10
// baseline (149.244 us; speedup 1.0000x reference)
//
#include <hip/hip_runtime.h>
#include <math.h>

#define BB 10
#define TT 12
#define FF 500
#define HH 200
#define G3 600
#define KP 224      // padded K for h (7*32)
#define NKS 7       // K-steps of 32
#define SLOTS 5     // j-tiles per wave (8 waves * 5 = 40); 4 in regs + 1 in LDS
#define RSLOTS 4
#define GHW 648     // ghf row stride in floats

// ws layout (float units):
#define WS_XW   0        // XW [120][600] fp32
#define WS_XWV  72000    // xw [120]
#define WS_FRAG 72128    // W_hh B-frags: 40 tiles * 7 ks * 64 lanes * 16B = 71680 dwords
#define WS_WHF  143808   // Wh hi/lo B-frags: 14 * 64 * 16B = 3584 dwords

typedef __attribute__((ext_vector_type(8))) short bf16x8;
typedef __attribute__((ext_vector_type(4))) float f32x4;

__device__ __forceinline__ unsigned short f2bf(float f) {
    unsigned int u = __float_as_uint(f);
    u = (u + 0x7fffu + ((u >> 16) & 1u)) >> 16;
    return (unsigned short)u;
}
__device__ __forceinline__ float bf2f(unsigned short h) {
    return __uint_as_float(((unsigned int)h) << 16);
}

// ---------------- K1: XW fp32, xw, W_hh B-frags (j = 40n + tile), Wh hi/lo frags ----
__global__ __launch_bounds__(256) void prep_kernel(
        const float* __restrict__ x, const float* __restrict__ wx,
        const float* __restrict__ W_ih, const float* __restrict__ W_hh,
        const float* __restrict__ Wh, float* __restrict__ ws) {
    int bl = blockIdx.x, tid = threadIdx.x;
    if (bl < 75) {
        // XW[bt][j] fp32 for j in [bl*8, bl*8+8)
        __shared__ __align__(16) float wsm[8][FF];
        int j0 = bl * 8;
        for (int idx = tid; idx < 8 * FF; idx += 256)
            wsm[idx / FF][idx % FF] = W_ih[(j0 + idx / FF) * FF + (idx % FF)];
        __syncthreads();
        for (int p = tid; p < BB * TT * 8; p += 256) {
            int bt = p >> 3, jj = p & 7;
            const float4* xr = (const float4*)(x + bt * FF);
            const float4* wr = (const float4*)&wsm[jj][0];
            float acc = 0.f;
            for (int c = 0; c < FF / 4; ++c) {
                float4 a = xr[c], b = wr[c];
                acc += a.x * b.x + a.y * b.y + a.z * b.z + a.w * b.w;
            }
            ws[WS_XW + bt * G3 + j0 + jj] = acc;
        }
    } else if (bl < 91) {
        // W_hh B-frags: dword d = ((tile*NKS+ks)*64+lane)*4+v ; k = ks*32+(lane>>4)*8+2v
        unsigned int* fr = (unsigned int*)(ws + WS_FRAG);
        int base = (bl - 75) * 4480;
        for (int q = tid; q < 4480; q += 256) {
            int d = base + q;
            int v = d & 3, lane = (d >> 2) & 63, pk = d >> 8;
            int ks = pk % NKS, tile = pk / NKS;
            int n = lane & 15;
            int k = ks * 32 + (lane >> 4) * 8 + 2 * v;
            unsigned int w = 0;
            if (k < HH && n < 15) {
                int j = 40 * n + tile;   // < 600
                w = (unsigned int)f2bf(W_hh[j * HH + k]) |
                    ((unsigned int)f2bf(W_hh[j * HH + k + 1]) << 16);
            }
            fr[d] = w;
        }
    } else if (bl < 99) {
        // xw[bt] = x[bt]·wx
        int dte = (bl - 91) * 15 + (tid >> 4), l = tid & 15;
        if (tid < 240) {
            float p = 0.f;
            for (int f = l; f < FF; f += 16) p += x[dte * FF + f] * wx[f];
            p += __shfl_xor(p, 8);
            p += __shfl_xor(p, 4);
            p += __shfl_xor(p, 2);
            p += __shfl_xor(p, 1);
            if (l == 0) ws[WS_XWV + dte] = p;
        }
    } else {
        // Wh hi/lo B-frags: d = ((ks*2+qq)*64+lane)*4+v ; n-col = t = lane&15
        unsigned int* fr = (unsigned int*)(ws + WS_WHF);
        for (int d = tid; d < 3584; d += 256) {
            int v = d & 3, lane = (d >> 2) & 63, pk = d >> 8;
            int qq = pk & 1, ks = pk >> 1;
            int t = lane & 15, k = ks * 32 + (lane >> 4) * 8 + 2 * v;
            unsigned int w = 0;
            if (t < TT && k < HH) {
                float f0 = Wh[t * HH + k], f1 = Wh[t * HH + k + 1];
                if (qq == 0) {
                    w = (unsigned int)f2bf(f0) | ((unsigned int)f2bf(f1) << 16);
                } else {
                    float l0 = f0 - bf2f(f2bf(f0)), l1 = f1 - bf2f(f2bf(f1));
                    w = (unsigned int)f2bf(l0) | ((unsigned int)f2bf(l1) << 16);
                }
            }
            fr[d] = w;
        }
    }
}

// hbf: bf16 h [16 rows(b)][KP], XOR-swizzled (ushort idx ^ (b&7)<<3)
__device__ __forceinline__ int hbf_idx(int r, int k) {
    return (r * KP + k) ^ ((r & 7) << 3);
}

// ---------------- K2: single-block 12-step recurrence, 8 waves ----------------
__global__ __attribute__((amdgpu_waves_per_eu(2, 2))) __launch_bounds__(512)
void recurrence_kernel(
        const float* __restrict__ guidance, const float* __restrict__ bh,
        const float* __restrict__ b_ih, const float* __restrict__ b_hh,
        const float* __restrict__ h0, const float* __restrict__ ws,
        float* __restrict__ out) {
    const float* XW  = ws + WS_XW;
    const float* xww = ws + WS_XWV;

    __shared__ __align__(16) float ghf[16 * GHW];           // 41.5 KB
    __shared__ __align__(16) unsigned short hbf[16 * KP];   // 7 KB
    __shared__ __align__(16) bf16x8 wlds[8][NKS][64];       // 57 KB (1 tile/wave)
    __shared__ __align__(16) bf16x8 wh_lds[2][NKS][64];     // 14 KB
    __shared__ __align__(16) float bsum_s[2 * HH];          // r,z gate bias sums
    __shared__ __align__(16) float bihn_s[HH];
    __shared__ __align__(16) float bhhn_s[HH];
    __shared__ float guid_s[BB][TT], zr_s[BB][TT], xw_s[BB][TT];
    __shared__ float a_w[8][TT][12];
    __shared__ float bh_s[TT];

    int tid = threadIdx.x, wv = tid >> 6, lane = tid & 63;
    int ar = lane & 15, kg = lane >> 4;

    // --- W_hh B-fragments: 4 tiles/wave -> regs (112), 1 tile/wave -> LDS ---
    bf16x8 bfr[RSLOTS][NKS];
    {
        const bf16x8* fragp = (const bf16x8*)(ws + WS_FRAG);
        #pragma unroll
        for (int s = 0; s < RSLOTS; ++s)
            #pragma unroll
            for (int ks = 0; ks < NKS; ++ks)
                bfr[s][ks] = fragp[((SLOTS * wv + s) * NKS + ks) * 64 + lane];
        #pragma unroll
        for (int ks = 0; ks < NKS; ++ks)
            wlds[wv][ks][lane] = fragp[((SLOTS * wv + RSLOTS) * NKS + ks) * 64 + lane];
        const bf16x8* whp = (const bf16x8*)(ws + WS_WHF);
        for (int u = tid; u < 2 * NKS * 64; u += 512) {
            int l = u & 63, pk = u >> 6;
            wh_lds[pk & 1][pk >> 1][l] = whp[u];
        }
    }
    // --- LDS init ---
    if (tid < BB * TT) {
        guid_s[tid / TT][tid % TT] = guidance[tid];
        xw_s[tid / TT][tid % TT]   = xww[tid];
    }
    for (int idx = tid; idx < 2 * HH; idx += 512) bsum_s[idx] = b_ih[idx] + b_hh[idx];
    for (int idx = tid; idx < HH; idx += 512) {
        bihn_s[idx] = b_ih[idx + 2 * HH];
        bhhn_s[idx] = b_hh[idx + 2 * HH];
    }
    if (tid < TT) bh_s[tid] = bh[tid];
    for (int idx = tid; idx < 16 * KP / 2; idx += 512) ((unsigned int*)hbf)[idx] = 0;
    float4 hq = (float4){0.f, 0.f, 0.f, 0.f};
    if (tid < 500) hq = *(const float4*)(h0 + (tid / 50) * HH + (tid % 50) * 4);
    __syncthreads();
    if (tid < 500) {
        int b = tid / 50, k = (tid % 50) * 4;
        unsigned int u01 = (unsigned int)f2bf(hq.x) | ((unsigned int)f2bf(hq.y) << 16);
        unsigned int u23 = (unsigned int)f2bf(hq.z) | ((unsigned int)f2bf(hq.w) << 16);
        *(uint2*)&hbf[hbf_idx(b, k)] = (uint2){u01, u23};
    }
    if (tid < BB) {
        float run = 0.f;
        for (int i = 0; i < TT; ++i) {
            zr_s[tid][i] = (run == 0.f) ? 1.f : 0.f;
            run += guid_s[tid][i];
        }
    }
    __syncthreads();

    bool vB = tid < 500;
    int bB = vB ? tid / 50 : 0;
    int cB = vB ? tid % 50 : 0;
    const float* xwbase = XW + bB * (TT * G3) + cB * 4;

    #pragma unroll 1
    for (int i = 0; i < TT; ++i) {
        // ---- A-frags ----
        bf16x8 ahi[NKS];
        #pragma unroll
        for (int ks = 0; ks < NKS; ++ks)
            ahi[ks] = *(const bf16x8*)&hbf[hbf_idx(ar, ks * 32 + kg * 8)];
        // ---- sc MFMA (2 parallel chains, hi/lo Wh) ----
        f32x4 sch = (f32x4){0.f, 0.f, 0.f, 0.f};
        f32x4 scl = (f32x4){0.f, 0.f, 0.f, 0.f};
        #pragma unroll
        for (int ks = 0; ks < NKS; ++ks) {
            sch = __builtin_amdgcn_mfma_f32_16x16x32_bf16(ahi[ks], wh_lds[0][ks][lane], sch, 0, 0, 0);
            scl = __builtin_amdgcn_mfma_f32_16x16x32_bf16(ahi[ks], wh_lds[1][ks][lane], scl, 0, 0, 0);
        }
        // ---- B2 MFMAs (independent; hide sc chain latency) ----
        {
            f32x4 acc[SLOTS];
            #pragma unroll
            for (int s = 0; s < RSLOTS; ++s) {
                acc[s] = (f32x4){0.f, 0.f, 0.f, 0.f};
                #pragma unroll
                for (int ks = 0; ks < NKS; ++ks)
                    acc[s] = __builtin_amdgcn_mfma_f32_16x16x32_bf16(ahi[ks], bfr[s][ks], acc[s], 0, 0, 0);
            }
            acc[RSLOTS] = (f32x4){0.f, 0.f, 0.f, 0.f};
            #pragma unroll
            for (int ks = 0; ks < NKS; ++ks) {
                bf16x8 bw = wlds[wv][ks][lane];
                acc[RSLOTS] = __builtin_amdgcn_mfma_f32_16x16x32_bf16(ahi[ks], bw, acc[RSLOTS], 0, 0, 0);
            }
            int xr = (kg & 3) << 2;
            int base0 = 40 * ar + 5 * wv;
            #pragma unroll
            for (int r = 0; r < 4; ++r) {
                int b = 4 * kg + r;
                if (b < BB) {
                    int base = b * GHW + base0;
                    #pragma unroll
                    for (int s = 0; s < SLOTS; ++s)
                        ghf[(base + s) ^ xr] = acc[s][r];
                }
            }
        }
        // ---- B1 chunk-0 loads: static addresses, issued BEFORE softmax ----
        float4 gi_r = (float4){0.f, 0.f, 0.f, 0.f};
        float4 gi_z = gi_r, gi_n = gi_r;
        float4 rA[3], zA[3], nA[3], rB[3], zB[3], nB[3];
        float a12[TT];
        auto ldchunk = [&](float4 (&r)[3], float4 (&z)[3], float4 (&n)[3], int t0) {
            #pragma unroll
            for (int u = 0; u < 3; ++u) {
                r[u] = *(const float4*)(xwbase + (t0 + u) * G3);
                z[u] = *(const float4*)(xwbase + (t0 + u) * G3 + HH);
                n[u] = *(const float4*)(xwbase + (t0 + u) * G3 + 2 * HH);
            }
        };
        auto fmachunk = [&](const float4 (&r)[3], const float4 (&z)[3],
                            const float4 (&n)[3], int t0) {
            #pragma unroll
            for (int u = 0; u < 3; ++u) {
                float aa = a12[t0 + u];
                gi_r.x += aa * r[u].x; gi_r.y += aa * r[u].y;
                gi_r.z += aa * r[u].z; gi_r.w += aa * r[u].w;
                gi_z.x += aa * z[u].x; gi_z.y += aa * z[u].y;
                gi_z.z += aa * z[u].z; gi_z.w += aa * z[u].w;
                gi_n.x += aa * n[u].x; gi_n.y += aa * n[u].y;
                gi_n.z += aa * n[u].z; gi_n.w += aa * n[u].w;
            }
        };
        if (vB) ldchunk(rA, zA, nA, 0);
        // ---- softmax over b (per t = ar), wave-local result ----
        {
            int t = ar;
            float vv[4], mx = -3e38f;
            #pragma unroll
            for (int r = 0; r < 4; ++r) {
                int b = 4 * kg + r;
                float val = -3e38f;
                if (b < BB && t < TT) {
                    float ge = (t == i) ? 1.f : (zr_s[b][i] != 0.f ? 1.f : guid_s[b][t]);
                    val = ge * xw_s[b][t] + sch[r] + scl[r] + bh_s[t];
                }
                vv[r] = val;
                mx = fmaxf(mx, val);
            }
            mx = fmaxf(mx, __shfl_xor(mx, 16));
            mx = fmaxf(mx, __shfl_xor(mx, 32));
            float ee[4], sum = 0.f;
            #pragma unroll
            for (int r = 0; r < 4; ++r) {
                ee[r] = (vv[r] > -1e37f) ? __expf(vv[r] - mx) : 0.f;
                sum += ee[r];
            }
            sum += __shfl_xor(sum, 16);
            sum += __shfl_xor(sum, 32);
            float inv = 1.f / sum;
            #pragma unroll
            for (int r = 0; r < 4; ++r) {
                int b = 4 * kg + r;
                if (b < BB && t < TT) a_w[wv][t][b] = (t <= i) ? ee[r] * inv : 0.f;
            }
        }
        // ---- B1: fixed 12-trip, software-pipelined (a_w[t>i]==0 makes it exact) ----
        if (vB) {
            #pragma unroll
            for (int t = 0; t < TT; ++t) a12[t] = a_w[wv][t][bB];
            ldchunk(rB, zB, nB, 3);
            fmachunk(rA, zA, nA, 0);
            ldchunk(rA, zA, nA, 6);
            fmachunk(rB, zB, nB, 3);
            ldchunk(rB, zB, nB, 9);
            fmachunk(rA, zA, nA, 6);
            fmachunk(rB, zB, nB, 9);
        }
        __syncthreads();   // bar1: ghf ready

        // ---- P3: GRU update; gi in regs, gh from ghf; hbf refresh ----
        if (vB) {
            int b = bB, k = cB * 4;
            int xr = ((b >> 2) & 3) << 2;
            float4 ghr = *(const float4*)&ghf[(b * GHW + k) ^ xr];
            float4 ghz = *(const float4*)&ghf[(b * GHW + k + HH) ^ xr];
            float4 ghn = *(const float4*)&ghf[(b * GHW + k + 2 * HH) ^ xr];
            float4 br4 = *(const float4*)&bsum_s[k];
            float4 bz4 = *(const float4*)&bsum_s[k + HH];
            float4 bni = *(const float4*)&bihn_s[k];
            float4 bnh = *(const float4*)&bhhn_s[k];
            float4 hn;
            float* pgir = (float*)&gi_r; float* pgiz = (float*)&gi_z; float* pgin = (float*)&gi_n;
            float* pghr = (float*)&ghr;  float* pghz = (float*)&ghz;  float* pghn = (float*)&ghn;
            float* pbr = (float*)&br4;   float* pbz = (float*)&bz4;
            float* pbi = (float*)&bni;   float* pbh = (float*)&bnh;
            float* ph  = (float*)&hq;    float* phn = (float*)&hn;
            #pragma unroll
            for (int e = 0; e < 4; ++e) {
                float r = 1.f / (1.f + __expf(-(pgir[e] + pghr[e] + pbr[e])));
                float z = 1.f / (1.f + __expf(-(pgiz[e] + pghz[e] + pbz[e])));
                float xx = pgin[e] + pbi[e] + r * (pghn[e] + pbh[e]);
                float e2 = __expf(2.f * xx);
                float n = 1.f - 2.f / (e2 + 1.f);
                phn[e] = (1.f - z) * n + z * ph[e];
            }
            hq = hn;
            unsigned int u01 = (unsigned int)f2bf(hn.x) | ((unsigned int)f2bf(hn.y) << 16);
            unsigned int u23 = (unsigned int)f2bf(hn.z) | ((unsigned int)f2bf(hn.w) << 16);
            *(uint2*)&hbf[hbf_idx(b, k * 1)] = (uint2){u01, u23};
        }
        __syncthreads();   // bar2: hbf ready for next step
    }

    if (vB) *(float4*)(out + bB * HH + cB * 4) = hq;
}

extern "C" void kernel_launch(void* const* d_in, const int* in_sizes, int n_in,
                              void* d_out, int out_size, void* d_ws, size_t ws_size,
                              hipStream_t stream) {
    (void)in_sizes; (void)n_in; (void)out_size; (void)ws_size;
    const float* x    = (const float*)d_in[0];
    const float* guid = (const float*)d_in[1];
    const float* wx   = (const float*)d_in[2];
    const float* Wh   = (const float*)d_in[3];
    const float* bh   = (const float*)d_in[4];
    const float* W_ih = (const float*)d_in[5];
    const float* W_hh = (const float*)d_in[6];
    const float* b_ih = (const float*)d_in[7];
    const float* b_hh = (const float*)d_in[8];
    const float* h0   = (const float*)d_in[9];
    float* ws  = (float*)d_ws;
    float* out = (float*)d_out;

    hipLaunchKernelGGL(prep_kernel, dim3(100), dim3(256), 0, stream,
                       x, wx, W_ih, W_hh, Wh, ws);
    hipLaunchKernelGGL(recurrence_kernel, dim3(1), dim3(512), 0, stream,
                       guid, bh, b_ih, b_hh, h0, ws, out);
}